// Round 1
// baseline (1207.744 us; speedup 1.0000x reference)
//
#include <hip/hip_runtime.h>
#include <cmath>

constexpr int D   = 96;
constexpr int C   = 12;
constexpr int P   = 11;   // 1 + 2*5
constexpr int NF  = 5;
constexpr int VOX = D * D * D;        // 884736
constexpr int SLICE4 = VOX * 3;       // float4s per p-slice of transposed grid

// ---------------------------------------------------------------------------
// Transpose [P*C][x][y][z] -> [P][x][y][z][C]  (channels contiguous per voxel)
// Reads are coalesced (z consecutive across lanes, per channel); writes are
// 48B/thread contiguous blocks -> full lines per wave, vectorized as float4.
// ---------------------------------------------------------------------------
__global__ __launch_bounds__(256) void transpose_kernel(const float* __restrict__ g,
                                                        float* __restrict__ gt) {
  int t = blockIdx.x * 256 + threadIdx.x;   // (p, x, y, z) flat
  if (t >= P * VOX) return;
  int p = t / VOX;
  int r = t - p * VOX;                      // x*9216 + y*96 + z
  const float* src = g + (size_t)p * C * VOX + r;
  float v[C];
#pragma unroll
  for (int c = 0; c < C; ++c) v[c] = src[(size_t)c * VOX];
  float4* dst = reinterpret_cast<float4*>(gt) + (size_t)p * SLICE4 + (size_t)r * 3;
  float4 a, b, d4;
  a.x  = v[0];  a.y  = v[1];  a.z  = v[2];  a.w  = v[3];
  b.x  = v[4];  b.y  = v[5];  b.z  = v[6];  b.w  = v[7];
  d4.x = v[8];  d4.y = v[9];  d4.z = v[10]; d4.w = v[11];
  dst[0] = a; dst[1] = b; dst[2] = d4;
}

// ---------------------------------------------------------------------------
// One thread per point: 11 trilinear gathers of 12 channels, mean -> out[n][12]
// TR=true reads the transposed layout in d_ws; TR=false reads native layout.
// ---------------------------------------------------------------------------
template <bool TR>
__global__ __launch_bounds__(256) void sample_kernel(
    const float* __restrict__ xyz, const float* __restrict__ g,
    const float* __restrict__ xyz_min, const float* __restrict__ xyz_max,
    float* __restrict__ out, int N) {
  int n = blockIdx.x * 256 + threadIdx.x;
  if (n >= N) return;

  float u[3];
#pragma unroll
  for (int d = 0; d < 3; ++d) {
    float mn = xyz_min[d], mx = xyz_max[d];
    u[d] = (xyz[3 * (size_t)n + d] - mn) * (2.0f / (mx - mn)) - 1.0f;
  }

  float acc[C];
#pragma unroll
  for (int c = 0; c < C; ++c) acc[c] = 0.0f;

  int p = 0;
  auto gather = [&](float ex, float ey, float ez) {
    float e[3] = {ex, ey, ez};
    int i0[3], i1[3];
    float w[3];
#pragma unroll
    for (int d = 0; d < 3; ++d) {
      float t = (e[d] + 1.0f) * (0.5f * (D - 1));
      int a = (int)floorf(t);
      a = a < 0 ? 0 : (a > D - 1 ? D - 1 : a);
      int b = a + 1 > D - 1 ? D - 1 : a + 1;
      i0[d] = a; i1[d] = b;
      w[d] = t - (float)a;
    }
    float wx0 = 1.0f - w[0], wx1 = w[0];
    float wy0 = 1.0f - w[1], wy1 = w[1];
    float wz0 = 1.0f - w[2], wz1 = w[2];

    if constexpr (TR) {
      const float4* b4 = reinterpret_cast<const float4*>(g) + (size_t)p * SLICE4;
      auto corner = [&](int ix, int iy, int iz, float wgt) {
        size_t o = (size_t)((ix * D + iy) * D + iz) * 3;
        float4 A = b4[o], Bv = b4[o + 1], Cv = b4[o + 2];
        acc[0]  += wgt * A.x;  acc[1]  += wgt * A.y;  acc[2]  += wgt * A.z;  acc[3]  += wgt * A.w;
        acc[4]  += wgt * Bv.x; acc[5]  += wgt * Bv.y; acc[6]  += wgt * Bv.z; acc[7]  += wgt * Bv.w;
        acc[8]  += wgt * Cv.x; acc[9]  += wgt * Cv.y; acc[10] += wgt * Cv.z; acc[11] += wgt * Cv.w;
      };
      corner(i0[0], i0[1], i0[2], wx0 * wy0 * wz0);
      corner(i0[0], i0[1], i1[2], wx0 * wy0 * wz1);
      corner(i0[0], i1[1], i0[2], wx0 * wy1 * wz0);
      corner(i0[0], i1[1], i1[2], wx0 * wy1 * wz1);
      corner(i1[0], i0[1], i0[2], wx1 * wy0 * wz0);
      corner(i1[0], i0[1], i1[2], wx1 * wy0 * wz1);
      corner(i1[0], i1[1], i0[2], wx1 * wy1 * wz0);
      corner(i1[0], i1[1], i1[2], wx1 * wy1 * wz1);
    } else {
      const float* gp = g + (size_t)p * C * VOX;
      auto corner = [&](int ix, int iy, int iz, float wgt) {
        int o = (ix * D + iy) * D + iz;
#pragma unroll
        for (int c = 0; c < C; ++c) acc[c] += wgt * gp[(size_t)c * VOX + o];
      };
      corner(i0[0], i0[1], i0[2], wx0 * wy0 * wz0);
      corner(i0[0], i0[1], i1[2], wx0 * wy0 * wz1);
      corner(i0[0], i1[1], i0[2], wx0 * wy1 * wz0);
      corner(i0[0], i1[1], i1[2], wx0 * wy1 * wz1);
      corner(i1[0], i0[1], i0[2], wx1 * wy0 * wz0);
      corner(i1[0], i0[1], i1[2], wx1 * wy0 * wz1);
      corner(i1[0], i1[1], i0[2], wx1 * wy1 * wz0);
      corner(i1[0], i1[1], i1[2], wx1 * wy1 * wz1);
    }
    ++p;
  };

  // p = 0: identity component
  gather(u[0], u[1], u[2]);

  // p = 1..10: sin/cos at freqs 1,2,4,8,16 via double-angle recurrence
  float s[3], co[3];
#pragma unroll
  for (int d = 0; d < 3; ++d) { s[d] = sinf(u[d]); co[d] = cosf(u[d]); }
  for (int f = 0; f < NF; ++f) {
    gather(s[0], s[1], s[2]);
    gather(co[0], co[1], co[2]);
    if (f < NF - 1) {
#pragma unroll
      for (int d = 0; d < 3; ++d) {
        float ns = 2.0f * s[d] * co[d];
        float nc = 1.0f - 2.0f * s[d] * s[d];
        s[d] = ns; co[d] = nc;
      }
    }
  }

  constexpr float inv = 1.0f / (float)P;
  float4 r0, r1, r2;
  r0.x = acc[0] * inv;  r0.y = acc[1] * inv;  r0.z = acc[2] * inv;  r0.w = acc[3] * inv;
  r1.x = acc[4] * inv;  r1.y = acc[5] * inv;  r1.z = acc[6] * inv;  r1.w = acc[7] * inv;
  r2.x = acc[8] * inv;  r2.y = acc[9] * inv;  r2.z = acc[10] * inv; r2.w = acc[11] * inv;
  float4* o4 = reinterpret_cast<float4*>(out + (size_t)n * C);
  o4[0] = r0; o4[1] = r1; o4[2] = r2;
}

extern "C" void kernel_launch(void* const* d_in, const int* in_sizes, int n_in,
                              void* d_out, int out_size, void* d_ws, size_t ws_size,
                              hipStream_t stream) {
  const float* xyz = (const float*)d_in[0];
  const float* grid = (const float*)d_in[1];
  const float* mn = (const float*)d_in[2];
  const float* mx = (const float*)d_in[3];
  float* out = (float*)d_out;
  int N = in_sizes[0] / 3;

  size_t need = (size_t)P * VOX * C * sizeof(float);   // ~467 MB
  int sblocks = (N + 255) / 256;
  if (ws_size >= need) {
    float* gt = (float*)d_ws;
    int tblocks = (P * VOX + 255) / 256;
    transpose_kernel<<<tblocks, 256, 0, stream>>>(grid, gt);
    sample_kernel<true><<<sblocks, 256, 0, stream>>>(xyz, gt, mn, mx, out, N);
  } else {
    sample_kernel<false><<<sblocks, 256, 0, stream>>>(xyz, grid, mn, mx, out, N);
  }
}

// Round 2
// 770.928 us; speedup vs baseline: 1.5666x; 1.5666x over previous
//
#include <hip/hip_runtime.h>
#include <hip/hip_fp16.h>
#include <cmath>

constexpr int D   = 96;
constexpr int C   = 12;
constexpr int P   = 11;   // 1 + 2*5
constexpr int NF  = 5;
constexpr int VOX = D * D * D;        // 884736

// ---------------------------------------------------------------------------
// Transpose + downconvert: [P*C][x][y][z] f32 -> [P][x][y][z][C] fp16
// 4 voxels per thread: 12x float4 coalesced reads, 6x uint4 contiguous writes.
// ---------------------------------------------------------------------------
__global__ __launch_bounds__(256) void transpose_fp16_kernel(
    const float* __restrict__ g, __half* __restrict__ gt) {
  constexpr int RPT = VOX / 4;                 // voxel-quads per p-slice
  int t = blockIdx.x * 256 + threadIdx.x;      // over P * RPT
  if (t >= P * RPT) return;
  int p = t / RPT;
  int r4 = (t - p * RPT) * 4;                  // base voxel within slice
  const float* src = g + (size_t)p * C * VOX + r4;

  float4 v[C];
#pragma unroll
  for (int c = 0; c < C; ++c)
    v[c] = *reinterpret_cast<const float4*>(src + (size_t)c * VOX);

  union { __half h[48]; uint4 u[6]; } pk;
#pragma unroll
  for (int j = 0; j < 4; ++j) {
#pragma unroll
    for (int c = 0; c < C; ++c) {
      float f = (j == 0) ? v[c].x : (j == 1) ? v[c].y : (j == 2) ? v[c].z : v[c].w;
      pk.h[j * C + c] = __float2half_rn(f);
    }
  }
  uint4* dst = reinterpret_cast<uint4*>(gt + ((size_t)p * VOX + r4) * C);
#pragma unroll
  for (int k = 0; k < 6; ++k) dst[k] = pk.u[k];
}

// ---------------------------------------------------------------------------
// One thread per point: 11 trilinear gathers of 12 fp16 channels, mean.
// Each (x,y) corner-pair loads the 48B z-pair as 6x dwordx2 (8B aligned).
// ---------------------------------------------------------------------------
__global__ __launch_bounds__(256) void sample_fp16_kernel(
    const float* __restrict__ xyz, const __half* __restrict__ g,
    const float* __restrict__ xyz_min, const float* __restrict__ xyz_max,
    float* __restrict__ out, int N) {
  int n = blockIdx.x * 256 + threadIdx.x;
  if (n >= N) return;

  float u[3];
#pragma unroll
  for (int d = 0; d < 3; ++d) {
    float mn = xyz_min[d], mx = xyz_max[d];
    u[d] = (xyz[3 * (size_t)n + d] - mn) * (2.0f / (mx - mn)) - 1.0f;
  }

  float acc[C];
#pragma unroll
  for (int c = 0; c < C; ++c) acc[c] = 0.0f;

  const ushort* gu = reinterpret_cast<const ushort*>(g);
  int p = 0;
  auto gather = [&](float ex, float ey, float ez) {
    // ez -> z (fastest dim), ey -> y, ex -> x  (matches grid_sample convention)
    float tz = (ez + 1.0f) * (0.5f * (D - 1));
    float ty = (ey + 1.0f) * (0.5f * (D - 1));
    float tx = (ex + 1.0f) * (0.5f * (D - 1));
    int z0 = (int)floorf(tz); z0 = z0 < 0 ? 0 : (z0 > D - 1 ? D - 1 : z0);
    int y0 = (int)floorf(ty); y0 = y0 < 0 ? 0 : (y0 > D - 1 ? D - 1 : y0);
    int x0 = (int)floorf(tx); x0 = x0 < 0 ? 0 : (x0 > D - 1 ? D - 1 : x0);
    int y1 = y0 + 1 > D - 1 ? D - 1 : y0 + 1;
    int x1 = x0 + 1 > D - 1 ? D - 1 : x0 + 1;
    float wz = tz - (float)z0, wy = ty - (float)y0, wx = tx - (float)x0;
    float wz0 = 1.0f - wz, wz1 = wz;
    float wy0 = 1.0f - wy, wy1 = wy;
    float wx0 = 1.0f - wx, wx1 = wx;

    size_t pbase = (size_t)p * VOX;
    auto region = [&](int ix, int iy, float wxy) {
      // z-pair: 24 halves starting at voxel (ix,iy,z0). The z0==95 case has
      // wz1 == 0, so the (harmless, in-allocation) overread is weight-0.
      size_t o = (pbase + (size_t)((ix * D + iy) * D + z0)) * C;
      const uint2* hp = reinterpret_cast<const uint2*>(gu + o);
      uint2 qa = hp[0], qb = hp[1], qc = hp[2];   // z0 ch 0..11
      uint2 qd = hp[3], qe = hp[4], qf = hp[5];   // z1 ch 0..11
      float a0 = wxy * wz0, a1 = wxy * wz1;
      auto acc2 = [&](unsigned lo, unsigned hi, int c) {
        __half2 hl = *reinterpret_cast<const __half2*>(&lo);
        __half2 hh = *reinterpret_cast<const __half2*>(&hi);
        float2 f0 = __half22float2(hl);
        float2 f1 = __half22float2(hh);
        acc[c]     = fmaf(a0, f0.x, fmaf(a1, f1.x, acc[c]));
        acc[c + 1] = fmaf(a0, f0.y, fmaf(a1, f1.y, acc[c + 1]));
      };
      acc2(qa.x, qd.x, 0);
      acc2(qa.y, qd.y, 2);
      acc2(qb.x, qe.x, 4);
      acc2(qb.y, qe.y, 6);
      acc2(qc.x, qf.x, 8);
      acc2(qc.y, qf.y, 10);
    };
    region(x0, y0, wx0 * wy0);
    region(x0, y1, wx0 * wy1);
    region(x1, y0, wx1 * wy0);
    region(x1, y1, wx1 * wy1);
    ++p;
  };

  // p = 0: identity component
  gather(u[0], u[1], u[2]);

  // p = 1..10: sin/cos at freqs 1,2,4,8,16 via double-angle recurrence
  float s[3], co[3];
#pragma unroll
  for (int d = 0; d < 3; ++d) { s[d] = sinf(u[d]); co[d] = cosf(u[d]); }
  for (int f = 0; f < NF; ++f) {
    gather(s[0], s[1], s[2]);
    gather(co[0], co[1], co[2]);
    if (f < NF - 1) {
#pragma unroll
      for (int d = 0; d < 3; ++d) {
        float ns = 2.0f * s[d] * co[d];
        float nc = 1.0f - 2.0f * s[d] * s[d];
        s[d] = ns; co[d] = nc;
      }
    }
  }

  constexpr float inv = 1.0f / (float)P;
  float4 r0, r1, r2;
  r0.x = acc[0] * inv;  r0.y = acc[1] * inv;  r0.z = acc[2] * inv;  r0.w = acc[3] * inv;
  r1.x = acc[4] * inv;  r1.y = acc[5] * inv;  r1.z = acc[6] * inv;  r1.w = acc[7] * inv;
  r2.x = acc[8] * inv;  r2.y = acc[9] * inv;  r2.z = acc[10] * inv; r2.w = acc[11] * inv;
  float4* o4 = reinterpret_cast<float4*>(out + (size_t)n * C);
  o4[0] = r0; o4[1] = r1; o4[2] = r2;
}

// ---------------------------------------------------------------------------
// Fallback (native fp32 layout) if workspace is too small — correctness net.
// ---------------------------------------------------------------------------
__global__ __launch_bounds__(256) void sample_naive_kernel(
    const float* __restrict__ xyz, const float* __restrict__ g,
    const float* __restrict__ xyz_min, const float* __restrict__ xyz_max,
    float* __restrict__ out, int N) {
  int n = blockIdx.x * 256 + threadIdx.x;
  if (n >= N) return;
  float u[3];
#pragma unroll
  for (int d = 0; d < 3; ++d) {
    float mn = xyz_min[d], mx = xyz_max[d];
    u[d] = (xyz[3 * (size_t)n + d] - mn) * (2.0f / (mx - mn)) - 1.0f;
  }
  float acc[C];
#pragma unroll
  for (int c = 0; c < C; ++c) acc[c] = 0.0f;
  int p = 0;
  auto gather = [&](float ex, float ey, float ez) {
    float e[3] = {ez, ey, ex};
    int i0[3], i1[3]; float w[3];
#pragma unroll
    for (int d = 0; d < 3; ++d) {
      float t = (e[d] + 1.0f) * (0.5f * (D - 1));
      int a = (int)floorf(t);
      a = a < 0 ? 0 : (a > D - 1 ? D - 1 : a);
      int b = a + 1 > D - 1 ? D - 1 : a + 1;
      i0[d] = a; i1[d] = b; w[d] = t - (float)a;
    }
    const float* gp = g + (size_t)p * C * VOX;
    auto corner = [&](int iz, int iy, int ix, float wgt) {
      int o = (ix * D + iy) * D + iz;
#pragma unroll
      for (int c = 0; c < C; ++c) acc[c] += wgt * gp[(size_t)c * VOX + o];
    };
    corner(i0[0], i0[1], i0[2], (1 - w[0]) * (1 - w[1]) * (1 - w[2]));
    corner(i1[0], i0[1], i0[2], w[0] * (1 - w[1]) * (1 - w[2]));
    corner(i0[0], i1[1], i0[2], (1 - w[0]) * w[1] * (1 - w[2]));
    corner(i1[0], i1[1], i0[2], w[0] * w[1] * (1 - w[2]));
    corner(i0[0], i0[1], i1[2], (1 - w[0]) * (1 - w[1]) * w[2]);
    corner(i1[0], i0[1], i1[2], w[0] * (1 - w[1]) * w[2]);
    corner(i0[0], i1[1], i1[2], (1 - w[0]) * w[1] * w[2]);
    corner(i1[0], i1[1], i1[2], w[0] * w[1] * w[2]);
    ++p;
  };
  gather(u[0], u[1], u[2]);
  float s[3], co[3];
#pragma unroll
  for (int d = 0; d < 3; ++d) { s[d] = sinf(u[d]); co[d] = cosf(u[d]); }
  for (int f = 0; f < NF; ++f) {
    gather(s[0], s[1], s[2]);
    gather(co[0], co[1], co[2]);
    if (f < NF - 1) {
#pragma unroll
      for (int d = 0; d < 3; ++d) {
        float ns = 2.0f * s[d] * co[d];
        float nc = 1.0f - 2.0f * s[d] * s[d];
        s[d] = ns; co[d] = nc;
      }
    }
  }
  constexpr float inv = 1.0f / (float)P;
#pragma unroll
  for (int c = 0; c < C; ++c) out[(size_t)n * C + c] = acc[c] * inv;
}

extern "C" void kernel_launch(void* const* d_in, const int* in_sizes, int n_in,
                              void* d_out, int out_size, void* d_ws, size_t ws_size,
                              hipStream_t stream) {
  const float* xyz = (const float*)d_in[0];
  const float* grid = (const float*)d_in[1];
  const float* mn = (const float*)d_in[2];
  const float* mx = (const float*)d_in[3];
  float* out = (float*)d_out;
  int N = in_sizes[0] / 3;

  size_t need = (size_t)P * VOX * C * sizeof(__half) + 256;   // ~233 MB + slack
  int sblocks = (N + 255) / 256;
  if (ws_size >= need) {
    __half* gt = (__half*)d_ws;
    int tthreads = P * (VOX / 4);
    int tblocks = (tthreads + 255) / 256;
    transpose_fp16_kernel<<<tblocks, 256, 0, stream>>>(grid, gt);
    sample_fp16_kernel<<<sblocks, 256, 0, stream>>>(xyz, gt, mn, mx, out, N);
  } else {
    sample_naive_kernel<<<sblocks, 256, 0, stream>>>(xyz, grid, mn, mx, out, N);
  }
}

// Round 3
// 737.360 us; speedup vs baseline: 1.6379x; 1.0455x over previous
//
#include <hip/hip_runtime.h>
#include <hip/hip_fp16.h>
#include <cmath>

constexpr int D   = 96;
constexpr int C   = 12;
constexpr int P   = 11;   // 1 + 2*5
constexpr int NF  = 5;
constexpr int VOX = D * D * D;        // 884736

// ---------------------------------------------------------------------------
// Transpose + downconvert: [P*C][x][y][z] f32 -> [P][x][y][z][C] fp16
// 4 voxels per thread: 12x float4 coalesced reads, 6x uint4 contiguous writes.
// ---------------------------------------------------------------------------
__global__ __launch_bounds__(256) void transpose_fp16_kernel(
    const float* __restrict__ g, __half* __restrict__ gt) {
  constexpr int RPT = VOX / 4;                 // voxel-quads per p-slice
  int t = blockIdx.x * 256 + threadIdx.x;      // over P * RPT
  if (t >= P * RPT) return;
  int p = t / RPT;
  int r4 = (t - p * RPT) * 4;                  // base voxel within slice
  const float* src = g + (size_t)p * C * VOX + r4;

  float4 v[C];
#pragma unroll
  for (int c = 0; c < C; ++c)
    v[c] = *reinterpret_cast<const float4*>(src + (size_t)c * VOX);

  union { __half h[48]; uint4 u[6]; } pk;
#pragma unroll
  for (int j = 0; j < 4; ++j) {
#pragma unroll
    for (int c = 0; c < C; ++c) {
      float f = (j == 0) ? v[c].x : (j == 1) ? v[c].y : (j == 2) ? v[c].z : v[c].w;
      pk.h[j * C + c] = __float2half_rn(f);
    }
  }
  uint4* dst = reinterpret_cast<uint4*>(gt + ((size_t)p * VOX + r4) * C);
#pragma unroll
  for (int k = 0; k < 6; ++k) dst[k] = pk.u[k];
}

// ---------------------------------------------------------------------------
// One thread per point: 11 trilinear gathers of 12 fp16 channels, mean.
// Each (x,y) region is a 48B z-pair loaded as 3x dwordx4 (8B-aligned base;
// gfx9+ global loads tolerate it). All 12 loads of a comp are issued before
// any accumulation consumes them (12-deep MLP per wave).
// ---------------------------------------------------------------------------
__global__ __launch_bounds__(256) void sample_fp16_kernel(
    const float* __restrict__ xyz, const __half* __restrict__ g,
    const float* __restrict__ xyz_min, const float* __restrict__ xyz_max,
    float* __restrict__ out, int N) {
  int n = blockIdx.x * 256 + threadIdx.x;
  if (n >= N) return;

  float u[3];
#pragma unroll
  for (int d = 0; d < 3; ++d) {
    float mn = xyz_min[d], mx = xyz_max[d];
    u[d] = (xyz[3 * (size_t)n + d] - mn) * (2.0f / (mx - mn)) - 1.0f;
  }

  float acc[C];
#pragma unroll
  for (int c = 0; c < C; ++c) acc[c] = 0.0f;

  const ushort* gu = reinterpret_cast<const ushort*>(g);
  int p = 0;
  auto gather = [&](float ex, float ey, float ez) {
    // ez -> z (fastest dim), ey -> y, ex -> x  (grid_sample 5D convention)
    float tz = (ez + 1.0f) * (0.5f * (D - 1));
    float ty = (ey + 1.0f) * (0.5f * (D - 1));
    float tx = (ex + 1.0f) * (0.5f * (D - 1));
    int z0 = (int)floorf(tz); z0 = z0 < 0 ? 0 : (z0 > D - 1 ? D - 1 : z0);
    int y0 = (int)floorf(ty); y0 = y0 < 0 ? 0 : (y0 > D - 1 ? D - 1 : y0);
    int x0 = (int)floorf(tx); x0 = x0 < 0 ? 0 : (x0 > D - 1 ? D - 1 : x0);
    int y1 = y0 + 1 > D - 1 ? D - 1 : y0 + 1;
    int x1 = x0 + 1 > D - 1 ? D - 1 : x0 + 1;
    float wz = tz - (float)z0, wy = ty - (float)y0, wx = tx - (float)x0;
    float wz0 = 1.0f - wz, wz1 = wz;
    float wy0 = 1.0f - wy, wy1 = wy;
    float wx0 = 1.0f - wx, wx1 = wx;

    size_t pbase = (size_t)p * VOX;
    // Region base addresses (half-index); each region = 48B (z-pair x 12ch).
    // z0==95 overreads 24B with weight 0 — stays inside the ws allocation.
    const uint4* r00 = reinterpret_cast<const uint4*>(gu + (pbase + (size_t)((x0 * D + y0) * D + z0)) * C);
    const uint4* r01 = reinterpret_cast<const uint4*>(gu + (pbase + (size_t)((x0 * D + y1) * D + z0)) * C);
    const uint4* r10 = reinterpret_cast<const uint4*>(gu + (pbase + (size_t)((x1 * D + y0) * D + z0)) * C);
    const uint4* r11 = reinterpret_cast<const uint4*>(gu + (pbase + (size_t)((x1 * D + y1) * D + z0)) * C);

    // Issue all 12 loads up front.
    uint4 a0 = r00[0], a1 = r00[1], a2 = r00[2];
    uint4 b0 = r01[0], b1 = r01[1], b2 = r01[2];
    uint4 c0 = r10[0], c1 = r10[1], c2 = r10[2];
    uint4 d0 = r11[0], d1 = r11[1], d2 = r11[2];

    auto acc2 = [&](unsigned lo, unsigned hi, float w0, float w1, int c) {
      __half2 hl = *reinterpret_cast<const __half2*>(&lo);
      __half2 hh = *reinterpret_cast<const __half2*>(&hi);
      float2 f0 = __half22float2(hl);
      float2 f1 = __half22float2(hh);
      acc[c]     = fmaf(w0, f0.x, fmaf(w1, f1.x, acc[c]));
      acc[c + 1] = fmaf(w0, f0.y, fmaf(w1, f1.y, acc[c + 1]));
    };
    // q0 = ch0..7 z0; q1 = ch8..11 z0, ch0..3 z1; q2 = ch4..11 z1
    auto region = [&](const uint4& q0, const uint4& q1, const uint4& q2, float wxy) {
      float w0 = wxy * wz0, w1 = wxy * wz1;
      acc2(q0.x, q1.z, w0, w1, 0);
      acc2(q0.y, q1.w, w0, w1, 2);
      acc2(q0.z, q2.x, w0, w1, 4);
      acc2(q0.w, q2.y, w0, w1, 6);
      acc2(q1.x, q2.z, w0, w1, 8);
      acc2(q1.y, q2.w, w0, w1, 10);
    };
    region(a0, a1, a2, wx0 * wy0);
    region(b0, b1, b2, wx0 * wy1);
    region(c0, c1, c2, wx1 * wy0);
    region(d0, d1, d2, wx1 * wy1);
    ++p;
  };

  // p = 0: identity component
  gather(u[0], u[1], u[2]);

  // p = 1..10: sin/cos at freqs 1,2,4,8,16 via double-angle recurrence
  float s[3], co[3];
#pragma unroll
  for (int d = 0; d < 3; ++d) { s[d] = sinf(u[d]); co[d] = cosf(u[d]); }
  for (int f = 0; f < NF; ++f) {
    gather(s[0], s[1], s[2]);
    gather(co[0], co[1], co[2]);
    if (f < NF - 1) {
#pragma unroll
      for (int d = 0; d < 3; ++d) {
        float ns = 2.0f * s[d] * co[d];
        float nc = 1.0f - 2.0f * s[d] * s[d];
        s[d] = ns; co[d] = nc;
      }
    }
  }

  constexpr float inv = 1.0f / (float)P;
  float4 r0, r1, r2;
  r0.x = acc[0] * inv;  r0.y = acc[1] * inv;  r0.z = acc[2] * inv;  r0.w = acc[3] * inv;
  r1.x = acc[4] * inv;  r1.y = acc[5] * inv;  r1.z = acc[6] * inv;  r1.w = acc[7] * inv;
  r2.x = acc[8] * inv;  r2.y = acc[9] * inv;  r2.z = acc[10] * inv; r2.w = acc[11] * inv;
  float4* o4 = reinterpret_cast<float4*>(out + (size_t)n * C);
  o4[0] = r0; o4[1] = r1; o4[2] = r2;
}

// ---------------------------------------------------------------------------
// Fallback (native fp32 layout) if workspace is too small — correctness net.
// ---------------------------------------------------------------------------
__global__ __launch_bounds__(256) void sample_naive_kernel(
    const float* __restrict__ xyz, const float* __restrict__ g,
    const float* __restrict__ xyz_min, const float* __restrict__ xyz_max,
    float* __restrict__ out, int N) {
  int n = blockIdx.x * 256 + threadIdx.x;
  if (n >= N) return;
  float u[3];
#pragma unroll
  for (int d = 0; d < 3; ++d) {
    float mn = xyz_min[d], mx = xyz_max[d];
    u[d] = (xyz[3 * (size_t)n + d] - mn) * (2.0f / (mx - mn)) - 1.0f;
  }
  float acc[C];
#pragma unroll
  for (int c = 0; c < C; ++c) acc[c] = 0.0f;
  int p = 0;
  auto gather = [&](float ex, float ey, float ez) {
    float e[3] = {ez, ey, ex};
    int i0[3], i1[3]; float w[3];
#pragma unroll
    for (int d = 0; d < 3; ++d) {
      float t = (e[d] + 1.0f) * (0.5f * (D - 1));
      int a = (int)floorf(t);
      a = a < 0 ? 0 : (a > D - 1 ? D - 1 : a);
      int b = a + 1 > D - 1 ? D - 1 : a + 1;
      i0[d] = a; i1[d] = b; w[d] = t - (float)a;
    }
    const float* gp = g + (size_t)p * C * VOX;
    auto corner = [&](int iz, int iy, int ix, float wgt) {
      int o = (ix * D + iy) * D + iz;
#pragma unroll
      for (int c = 0; c < C; ++c) acc[c] += wgt * gp[(size_t)c * VOX + o];
    };
    corner(i0[0], i0[1], i0[2], (1 - w[0]) * (1 - w[1]) * (1 - w[2]));
    corner(i1[0], i0[1], i0[2], w[0] * (1 - w[1]) * (1 - w[2]));
    corner(i0[0], i1[1], i0[2], (1 - w[0]) * w[1] * (1 - w[2]));
    corner(i1[0], i1[1], i0[2], w[0] * w[1] * (1 - w[2]));
    corner(i0[0], i0[1], i1[2], (1 - w[0]) * (1 - w[1]) * w[2]);
    corner(i1[0], i0[1], i1[2], w[0] * (1 - w[1]) * w[2]);
    corner(i0[0], i1[1], i1[2], (1 - w[0]) * w[1] * w[2]);
    corner(i1[0], i1[1], i1[2], w[0] * w[1] * w[2]);
    ++p;
  };
  gather(u[0], u[1], u[2]);
  float s[3], co[3];
#pragma unroll
  for (int d = 0; d < 3; ++d) { s[d] = sinf(u[d]); co[d] = cosf(u[d]); }
  for (int f = 0; f < NF; ++f) {
    gather(s[0], s[1], s[2]);
    gather(co[0], co[1], co[2]);
    if (f < NF - 1) {
#pragma unroll
      for (int d = 0; d < 3; ++d) {
        float ns = 2.0f * s[d] * co[d];
        float nc = 1.0f - 2.0f * s[d] * s[d];
        s[d] = ns; co[d] = nc;
      }
    }
  }
  constexpr float inv = 1.0f / (float)P;
#pragma unroll
  for (int c = 0; c < C; ++c) out[(size_t)n * C + c] = acc[c] * inv;
}

extern "C" void kernel_launch(void* const* d_in, const int* in_sizes, int n_in,
                              void* d_out, int out_size, void* d_ws, size_t ws_size,
                              hipStream_t stream) {
  const float* xyz = (const float*)d_in[0];
  const float* grid = (const float*)d_in[1];
  const float* mn = (const float*)d_in[2];
  const float* mx = (const float*)d_in[3];
  float* out = (float*)d_out;
  int N = in_sizes[0] / 3;

  size_t need = (size_t)P * VOX * C * sizeof(__half) + 256;   // ~233 MB + slack
  int sblocks = (N + 255) / 256;
  if (ws_size >= need) {
    __half* gt = (__half*)d_ws;
    int tthreads = P * (VOX / 4);
    int tblocks = (tthreads + 255) / 256;
    transpose_fp16_kernel<<<tblocks, 256, 0, stream>>>(grid, gt);
    sample_fp16_kernel<<<sblocks, 256, 0, stream>>>(xyz, gt, mn, mx, out, N);
  } else {
    sample_naive_kernel<<<sblocks, 256, 0, stream>>>(xyz, grid, mn, mx, out, N);
  }
}

// Round 4
// 577.331 us; speedup vs baseline: 2.0919x; 1.2772x over previous
//
#include <hip/hip_runtime.h>
#include <hip/hip_fp16.h>
#include <cmath>

constexpr int D   = 96;
constexpr int C   = 12;
constexpr int P   = 11;   // 1 + 2*5
constexpr int NF  = 5;
constexpr int VOX = D * D * D;        // 884736
constexpr int CELLS = 32 * 32 * 32;   // sort buckets

// ---------------------------------------------------------------------------
// Transpose + downconvert: [P*C][x][y][z] f32 -> [P][x][y][z][C] fp16
// ---------------------------------------------------------------------------
__global__ __launch_bounds__(256) void transpose_fp16_kernel(
    const float* __restrict__ g, __half* __restrict__ gt) {
  constexpr int RPT = VOX / 4;
  int t = blockIdx.x * 256 + threadIdx.x;
  if (t >= P * RPT) return;
  int p = t / RPT;
  int r4 = (t - p * RPT) * 4;
  const float* src = g + (size_t)p * C * VOX + r4;

  float4 v[C];
#pragma unroll
  for (int c = 0; c < C; ++c)
    v[c] = *reinterpret_cast<const float4*>(src + (size_t)c * VOX);

  union { __half h[48]; uint4 u[6]; } pk;
#pragma unroll
  for (int j = 0; j < 4; ++j) {
#pragma unroll
    for (int c = 0; c < C; ++c) {
      float f = (j == 0) ? v[c].x : (j == 1) ? v[c].y : (j == 2) ? v[c].z : v[c].w;
      pk.h[j * C + c] = __float2half_rn(f);
    }
  }
  uint4* dst = reinterpret_cast<uint4*>(gt + ((size_t)p * VOX + r4) * C);
#pragma unroll
  for (int k = 0; k < 6; ++k) dst[k] = pk.u[k];
}

// ---------------------------------------------------------------------------
// Spatial binning: 32^3 Morton cells.
// ---------------------------------------------------------------------------
__device__ __forceinline__ unsigned spread5(unsigned v) {
  v &= 31u;
  v = (v | (v << 8)) & 0x100Fu;
  v = (v | (v << 4)) & 0x10C3u;
  v = (v | (v << 2)) & 0x1249u;
  return v;
}

__device__ __forceinline__ unsigned cell_of(const float* __restrict__ xyz, int n,
                                            const float* __restrict__ mn,
                                            const float* __restrict__ mx) {
  unsigned cc[3];
#pragma unroll
  for (int d = 0; d < 3; ++d) {
    float u = (xyz[3 * (size_t)n + d] - mn[d]) / (mx[d] - mn[d]);  // [0,1]
    int c = (int)(u * 32.0f);
    c = c < 0 ? 0 : (c > 31 ? 31 : c);
    cc[d] = (unsigned)c;
  }
  return spread5(cc[0]) | (spread5(cc[1]) << 1) | (spread5(cc[2]) << 2);
}

__global__ __launch_bounds__(256) void count_kernel(
    const float* __restrict__ xyz, const float* __restrict__ mn,
    const float* __restrict__ mx, unsigned* __restrict__ counts, int N) {
  int n = blockIdx.x * 256 + threadIdx.x;
  if (n >= N) return;
  atomicAdd(&counts[cell_of(xyz, n, mn, mx)], 1u);
}

// Single-block exclusive scan of CELLS (=32768) counters.
__global__ __launch_bounds__(1024) void scan_kernel(
    const unsigned* __restrict__ counts, unsigned* __restrict__ offsets) {
  __shared__ unsigned part[1024];
  int t = threadIdx.x;
  unsigned base = t * (CELLS / 1024);
  unsigned local[CELLS / 1024];
  unsigned s = 0;
#pragma unroll
  for (int i = 0; i < CELLS / 1024; ++i) { local[i] = s; s += counts[base + i]; }
  part[t] = s;
  __syncthreads();
  for (int off = 1; off < 1024; off <<= 1) {
    unsigned v = (t >= off) ? part[t - off] : 0u;
    __syncthreads();
    part[t] += v;
    __syncthreads();
  }
  unsigned prev = (t == 0) ? 0u : part[t - 1];
#pragma unroll
  for (int i = 0; i < CELLS / 1024; ++i) offsets[base + i] = prev + local[i];
}

// Scatter points into cell-sorted order: rec = {x, y, z, bits(orig_idx)}.
__global__ __launch_bounds__(256) void scatter_kernel(
    const float* __restrict__ xyz, const float* __restrict__ mn,
    const float* __restrict__ mx, unsigned* __restrict__ offsets,
    float4* __restrict__ sorted, int N) {
  int n = blockIdx.x * 256 + threadIdx.x;
  if (n >= N) return;
  unsigned cell = cell_of(xyz, n, mn, mx);
  unsigned slot = atomicAdd(&offsets[cell], 1u);
  float4 rec;
  rec.x = xyz[3 * (size_t)n + 0];
  rec.y = xyz[3 * (size_t)n + 1];
  rec.z = xyz[3 * (size_t)n + 2];
  rec.w = __uint_as_float((unsigned)n);
  sorted[slot] = rec;
}

// ---------------------------------------------------------------------------
// Sample kernel over the sorted list; writes out[orig_idx].
// ---------------------------------------------------------------------------
__global__ __launch_bounds__(256) void sample_sorted_kernel(
    const float4* __restrict__ pts, const __half* __restrict__ g,
    const float* __restrict__ xyz_min, const float* __restrict__ xyz_max,
    float* __restrict__ out, int N) {
  // XCD-bijective chunked block swizzle: each XCD gets a contiguous chunk of
  // the (spatially sorted) block range -> per-XCD L2 holds a compact region.
  unsigned nwg = gridDim.x, bid = blockIdx.x;
  unsigned q = nwg / 8u, r = nwg % 8u;
  unsigned xcd = bid % 8u, j = bid / 8u;
  unsigned swz = (xcd < r ? xcd * (q + 1u) : r * (q + 1u) + (xcd - r) * q) + j;
  int n = swz * 256 + threadIdx.x;
  if (n >= N) return;

  float4 rec = pts[n];
  unsigned oidx = __float_as_uint(rec.w);
  float in[3] = {rec.x, rec.y, rec.z};
  float u[3];
#pragma unroll
  for (int d = 0; d < 3; ++d) {
    float mn = xyz_min[d], mx = xyz_max[d];
    u[d] = (in[d] - mn) * (2.0f / (mx - mn)) - 1.0f;
  }

  float acc[C];
#pragma unroll
  for (int c = 0; c < C; ++c) acc[c] = 0.0f;

  const ushort* gu = reinterpret_cast<const ushort*>(g);
  int p = 0;
  auto gather = [&](float ex, float ey, float ez) {
    float tz = (ez + 1.0f) * (0.5f * (D - 1));
    float ty = (ey + 1.0f) * (0.5f * (D - 1));
    float tx = (ex + 1.0f) * (0.5f * (D - 1));
    int z0 = (int)floorf(tz); z0 = z0 < 0 ? 0 : (z0 > D - 1 ? D - 1 : z0);
    int y0 = (int)floorf(ty); y0 = y0 < 0 ? 0 : (y0 > D - 1 ? D - 1 : y0);
    int x0 = (int)floorf(tx); x0 = x0 < 0 ? 0 : (x0 > D - 1 ? D - 1 : x0);
    int y1 = y0 + 1 > D - 1 ? D - 1 : y0 + 1;
    int x1 = x0 + 1 > D - 1 ? D - 1 : x0 + 1;
    float wz = tz - (float)z0, wy = ty - (float)y0, wx = tx - (float)x0;
    float wz0 = 1.0f - wz, wz1 = wz;
    float wy0 = 1.0f - wy, wy1 = wy;
    float wx0 = 1.0f - wx, wx1 = wx;

    size_t pbase = (size_t)p * VOX;
    // 48B z-pair regions (z0==95 overread is weight-0, stays in-allocation).
    const uint4* r00 = reinterpret_cast<const uint4*>(gu + (pbase + (size_t)((x0 * D + y0) * D + z0)) * C);
    const uint4* r01 = reinterpret_cast<const uint4*>(gu + (pbase + (size_t)((x0 * D + y1) * D + z0)) * C);
    const uint4* r10 = reinterpret_cast<const uint4*>(gu + (pbase + (size_t)((x1 * D + y0) * D + z0)) * C);
    const uint4* r11 = reinterpret_cast<const uint4*>(gu + (pbase + (size_t)((x1 * D + y1) * D + z0)) * C);

    uint4 a0 = r00[0], a1 = r00[1], a2 = r00[2];
    uint4 b0 = r01[0], b1 = r01[1], b2 = r01[2];
    uint4 c0 = r10[0], c1 = r10[1], c2 = r10[2];
    uint4 d0 = r11[0], d1 = r11[1], d2 = r11[2];

    auto acc2 = [&](unsigned lo, unsigned hi, float w0, float w1, int c) {
      __half2 hl = *reinterpret_cast<const __half2*>(&lo);
      __half2 hh = *reinterpret_cast<const __half2*>(&hi);
      float2 f0 = __half22float2(hl);
      float2 f1 = __half22float2(hh);
      acc[c]     = fmaf(w0, f0.x, fmaf(w1, f1.x, acc[c]));
      acc[c + 1] = fmaf(w0, f0.y, fmaf(w1, f1.y, acc[c + 1]));
    };
    auto region = [&](const uint4& q0, const uint4& q1, const uint4& q2, float wxy) {
      float w0 = wxy * wz0, w1 = wxy * wz1;
      acc2(q0.x, q1.z, w0, w1, 0);
      acc2(q0.y, q1.w, w0, w1, 2);
      acc2(q0.z, q2.x, w0, w1, 4);
      acc2(q0.w, q2.y, w0, w1, 6);
      acc2(q1.x, q2.z, w0, w1, 8);
      acc2(q1.y, q2.w, w0, w1, 10);
    };
    region(a0, a1, a2, wx0 * wy0);
    region(b0, b1, b2, wx0 * wy1);
    region(c0, c1, c2, wx1 * wy0);
    region(d0, d1, d2, wx1 * wy1);
    ++p;
  };

  gather(u[0], u[1], u[2]);
  float s[3], co[3];
#pragma unroll
  for (int d = 0; d < 3; ++d) { s[d] = sinf(u[d]); co[d] = cosf(u[d]); }
  for (int f = 0; f < NF; ++f) {
    gather(s[0], s[1], s[2]);
    gather(co[0], co[1], co[2]);
    if (f < NF - 1) {
#pragma unroll
      for (int d = 0; d < 3; ++d) {
        float ns = 2.0f * s[d] * co[d];
        float nc = 1.0f - 2.0f * s[d] * s[d];
        s[d] = ns; co[d] = nc;
      }
    }
  }

  constexpr float inv = 1.0f / (float)P;
  float4 r0, r1, r2;
  r0.x = acc[0] * inv;  r0.y = acc[1] * inv;  r0.z = acc[2] * inv;  r0.w = acc[3] * inv;
  r1.x = acc[4] * inv;  r1.y = acc[5] * inv;  r1.z = acc[6] * inv;  r1.w = acc[7] * inv;
  r2.x = acc[8] * inv;  r2.y = acc[9] * inv;  r2.z = acc[10] * inv; r2.w = acc[11] * inv;
  float4* o4 = reinterpret_cast<float4*>(out + (size_t)oidx * C);
  o4[0] = r0; o4[1] = r1; o4[2] = r2;
}

// ---------------------------------------------------------------------------
// Unsorted fp16 path (round-3 behavior) — used if ws can't fit sort arrays.
// ---------------------------------------------------------------------------
__global__ __launch_bounds__(256) void sample_fp16_kernel(
    const float* __restrict__ xyz, const __half* __restrict__ g,
    const float* __restrict__ xyz_min, const float* __restrict__ xyz_max,
    float* __restrict__ out, int N) {
  int n = blockIdx.x * 256 + threadIdx.x;
  if (n >= N) return;
  float u[3];
#pragma unroll
  for (int d = 0; d < 3; ++d) {
    float mn = xyz_min[d], mx = xyz_max[d];
    u[d] = (xyz[3 * (size_t)n + d] - mn) * (2.0f / (mx - mn)) - 1.0f;
  }
  float acc[C];
#pragma unroll
  for (int c = 0; c < C; ++c) acc[c] = 0.0f;
  const ushort* gu = reinterpret_cast<const ushort*>(g);
  int p = 0;
  auto gather = [&](float ex, float ey, float ez) {
    float tz = (ez + 1.0f) * (0.5f * (D - 1));
    float ty = (ey + 1.0f) * (0.5f * (D - 1));
    float tx = (ex + 1.0f) * (0.5f * (D - 1));
    int z0 = (int)floorf(tz); z0 = z0 < 0 ? 0 : (z0 > D - 1 ? D - 1 : z0);
    int y0 = (int)floorf(ty); y0 = y0 < 0 ? 0 : (y0 > D - 1 ? D - 1 : y0);
    int x0 = (int)floorf(tx); x0 = x0 < 0 ? 0 : (x0 > D - 1 ? D - 1 : x0);
    int y1 = y0 + 1 > D - 1 ? D - 1 : y0 + 1;
    int x1 = x0 + 1 > D - 1 ? D - 1 : x0 + 1;
    float wz = tz - (float)z0, wy = ty - (float)y0, wx = tx - (float)x0;
    float wz0 = 1.0f - wz, wz1 = wz;
    float wy0 = 1.0f - wy, wy1 = wy;
    float wx0 = 1.0f - wx, wx1 = wx;
    size_t pbase = (size_t)p * VOX;
    const uint4* r00 = reinterpret_cast<const uint4*>(gu + (pbase + (size_t)((x0 * D + y0) * D + z0)) * C);
    const uint4* r01 = reinterpret_cast<const uint4*>(gu + (pbase + (size_t)((x0 * D + y1) * D + z0)) * C);
    const uint4* r10 = reinterpret_cast<const uint4*>(gu + (pbase + (size_t)((x1 * D + y0) * D + z0)) * C);
    const uint4* r11 = reinterpret_cast<const uint4*>(gu + (pbase + (size_t)((x1 * D + y1) * D + z0)) * C);
    uint4 a0 = r00[0], a1 = r00[1], a2 = r00[2];
    uint4 b0 = r01[0], b1 = r01[1], b2 = r01[2];
    uint4 c0 = r10[0], c1 = r10[1], c2 = r10[2];
    uint4 d0 = r11[0], d1 = r11[1], d2 = r11[2];
    auto acc2 = [&](unsigned lo, unsigned hi, float w0, float w1, int c) {
      __half2 hl = *reinterpret_cast<const __half2*>(&lo);
      __half2 hh = *reinterpret_cast<const __half2*>(&hi);
      float2 f0 = __half22float2(hl);
      float2 f1 = __half22float2(hh);
      acc[c]     = fmaf(w0, f0.x, fmaf(w1, f1.x, acc[c]));
      acc[c + 1] = fmaf(w0, f0.y, fmaf(w1, f1.y, acc[c + 1]));
    };
    auto region = [&](const uint4& q0, const uint4& q1, const uint4& q2, float wxy) {
      float w0 = wxy * wz0, w1 = wxy * wz1;
      acc2(q0.x, q1.z, w0, w1, 0);
      acc2(q0.y, q1.w, w0, w1, 2);
      acc2(q0.z, q2.x, w0, w1, 4);
      acc2(q0.w, q2.y, w0, w1, 6);
      acc2(q1.x, q2.z, w0, w1, 8);
      acc2(q1.y, q2.w, w0, w1, 10);
    };
    region(a0, a1, a2, wx0 * wy0);
    region(b0, b1, b2, wx0 * wy1);
    region(c0, c1, c2, wx1 * wy0);
    region(d0, d1, d2, wx1 * wy1);
    ++p;
  };
  gather(u[0], u[1], u[2]);
  float s[3], co[3];
#pragma unroll
  for (int d = 0; d < 3; ++d) { s[d] = sinf(u[d]); co[d] = cosf(u[d]); }
  for (int f = 0; f < NF; ++f) {
    gather(s[0], s[1], s[2]);
    gather(co[0], co[1], co[2]);
    if (f < NF - 1) {
#pragma unroll
      for (int d = 0; d < 3; ++d) {
        float ns = 2.0f * s[d] * co[d];
        float nc = 1.0f - 2.0f * s[d] * s[d];
        s[d] = ns; co[d] = nc;
      }
    }
  }
  constexpr float inv = 1.0f / (float)P;
  float4 r0, r1, r2;
  r0.x = acc[0] * inv;  r0.y = acc[1] * inv;  r0.z = acc[2] * inv;  r0.w = acc[3] * inv;
  r1.x = acc[4] * inv;  r1.y = acc[5] * inv;  r1.z = acc[6] * inv;  r1.w = acc[7] * inv;
  r2.x = acc[8] * inv;  r2.y = acc[9] * inv;  r2.z = acc[10] * inv; r2.w = acc[11] * inv;
  float4* o4 = reinterpret_cast<float4*>(out + (size_t)n * C);
  o4[0] = r0; o4[1] = r1; o4[2] = r2;
}

// Last-resort naive fp32 path.
__global__ __launch_bounds__(256) void sample_naive_kernel(
    const float* __restrict__ xyz, const float* __restrict__ g,
    const float* __restrict__ xyz_min, const float* __restrict__ xyz_max,
    float* __restrict__ out, int N) {
  int n = blockIdx.x * 256 + threadIdx.x;
  if (n >= N) return;
  float u[3];
#pragma unroll
  for (int d = 0; d < 3; ++d) {
    float mn = xyz_min[d], mx = xyz_max[d];
    u[d] = (xyz[3 * (size_t)n + d] - mn) * (2.0f / (mx - mn)) - 1.0f;
  }
  float acc[C];
#pragma unroll
  for (int c = 0; c < C; ++c) acc[c] = 0.0f;
  int p = 0;
  auto gather = [&](float ex, float ey, float ez) {
    float e[3] = {ez, ey, ex};
    int i0[3], i1[3]; float w[3];
#pragma unroll
    for (int d = 0; d < 3; ++d) {
      float t = (e[d] + 1.0f) * (0.5f * (D - 1));
      int a = (int)floorf(t);
      a = a < 0 ? 0 : (a > D - 1 ? D - 1 : a);
      int b = a + 1 > D - 1 ? D - 1 : a + 1;
      i0[d] = a; i1[d] = b; w[d] = t - (float)a;
    }
    const float* gp = g + (size_t)p * C * VOX;
    auto corner = [&](int iz, int iy, int ix, float wgt) {
      int o = (ix * D + iy) * D + iz;
#pragma unroll
      for (int c = 0; c < C; ++c) acc[c] += wgt * gp[(size_t)c * VOX + o];
    };
    corner(i0[0], i0[1], i0[2], (1 - w[0]) * (1 - w[1]) * (1 - w[2]));
    corner(i1[0], i0[1], i0[2], w[0] * (1 - w[1]) * (1 - w[2]));
    corner(i0[0], i1[1], i0[2], (1 - w[0]) * w[1] * (1 - w[2]));
    corner(i1[0], i1[1], i0[2], w[0] * w[1] * (1 - w[2]));
    corner(i0[0], i0[1], i1[2], (1 - w[0]) * (1 - w[1]) * w[2]);
    corner(i1[0], i0[1], i1[2], w[0] * (1 - w[1]) * w[2]);
    corner(i0[0], i1[1], i1[2], (1 - w[0]) * w[1] * w[2]);
    corner(i1[0], i1[1], i1[2], w[0] * w[1] * w[2]);
    ++p;
  };
  gather(u[0], u[1], u[2]);
  float s[3], co[3];
#pragma unroll
  for (int d = 0; d < 3; ++d) { s[d] = sinf(u[d]); co[d] = cosf(u[d]); }
  for (int f = 0; f < NF; ++f) {
    gather(s[0], s[1], s[2]);
    gather(co[0], co[1], co[2]);
    if (f < NF - 1) {
#pragma unroll
      for (int d = 0; d < 3; ++d) {
        float ns = 2.0f * s[d] * co[d];
        float nc = 1.0f - 2.0f * s[d] * s[d];
        s[d] = ns; co[d] = nc;
      }
    }
  }
  constexpr float inv = 1.0f / (float)P;
#pragma unroll
  for (int c = 0; c < C; ++c) out[(size_t)n * C + c] = acc[c] * inv;
}

extern "C" void kernel_launch(void* const* d_in, const int* in_sizes, int n_in,
                              void* d_out, int out_size, void* d_ws, size_t ws_size,
                              hipStream_t stream) {
  const float* xyz = (const float*)d_in[0];
  const float* grid = (const float*)d_in[1];
  const float* mn = (const float*)d_in[2];
  const float* mx = (const float*)d_in[3];
  float* out = (float*)d_out;
  int N = in_sizes[0] / 3;

  size_t gt_bytes = (size_t)P * VOX * C * sizeof(__half);        // ~233 MB
  size_t sorted_bytes = (size_t)N * sizeof(float4);              // 12.8 MB
  size_t cnt_bytes = (size_t)CELLS * sizeof(unsigned);
  size_t need_sorted = sorted_bytes + gt_bytes + 2 * cnt_bytes + 1024;
  size_t need_plain  = gt_bytes + 256;

  int sblocks = (N + 255) / 256;
  int tblocks = (P * (VOX / 4) + 255) / 256;

  if (ws_size >= need_sorted) {
    char* w = (char*)d_ws;
    float4*   sorted  = (float4*)w;                  w += sorted_bytes;
    __half*   gt      = (__half*)w;                  w += gt_bytes;
    unsigned* counts  = (unsigned*)w;                w += cnt_bytes;
    unsigned* offsets = (unsigned*)w;

    transpose_fp16_kernel<<<tblocks, 256, 0, stream>>>(grid, gt);
    hipMemsetAsync(counts, 0, cnt_bytes, stream);
    count_kernel<<<sblocks, 256, 0, stream>>>(xyz, mn, mx, counts, N);
    scan_kernel<<<1, 1024, 0, stream>>>(counts, offsets);
    scatter_kernel<<<sblocks, 256, 0, stream>>>(xyz, mn, mx, offsets, sorted, N);
    sample_sorted_kernel<<<sblocks, 256, 0, stream>>>(sorted, gt, mn, mx, out, N);
  } else if (ws_size >= need_plain) {
    __half* gt = (__half*)d_ws;
    transpose_fp16_kernel<<<tblocks, 256, 0, stream>>>(grid, gt);
    sample_fp16_kernel<<<sblocks, 256, 0, stream>>>(xyz, gt, mn, mx, out, N);
  } else {
    sample_naive_kernel<<<sblocks, 256, 0, stream>>>(xyz, grid, mn, mx, out, N);
  }
}